// Round 10
// baseline (1248.817 us; speedup 1.0000x reference)
//
#include <hip/hip_runtime.h>
#include <hip/hip_bf16.h>
#include <math.h>

using short8 = __attribute__((ext_vector_type(8))) short;
using f32x4  = __attribute__((ext_vector_type(4))) float;

#define PSTRIDE 2048   // per-batch neighbor table stride

__device__ __forceinline__ short f2bf(float f) {
    __hip_bfloat16 h = __float2bfloat16(f);   // RNE; pairs fuse to v_cvt_pk_bf16_f32
    return *reinterpret_cast<short*>(&h);
}

// ---------------------------------------------------------------------------
// Graph prep: binned CSR build (dst-binned, 32 nodes per bin)
// pairs entry packed: s (bits 0..16) | (d&31)<<27
// ---------------------------------------------------------------------------

__global__ void map_scatter_k(const int* __restrict__ mapping, int* __restrict__ map_idx, int B)
{
    int b = blockIdx.x * blockDim.x + threadIdx.x;
    if (b < B) map_idx[mapping[b]] = b;
}

__launch_bounds__(1024)
__global__ void bin_count_k(const int* __restrict__ dst, int E, int* __restrict__ bin_cnt)
{
    __shared__ int h[4096];
    for (int i = threadIdx.x; i < 4096; i += 1024) h[i] = 0;
    __syncthreads();
    int base = blockIdx.x * 32768;
#pragma unroll
    for (int i = 0; i < 32; ++i) {
        int e = base + i * 1024 + threadIdx.x;
        if (e < E) atomicAdd(&h[dst[e] >> 5], 1);
    }
    __syncthreads();
    for (int i = threadIdx.x; i < 4096; i += 1024) {
        int c = h[i];
        if (c) atomicAdd(&bin_cnt[i], c);
    }
}

__launch_bounds__(1024)
__global__ void scan_bins_k(const int* __restrict__ cnt, int* __restrict__ off,
                            int* __restrict__ cur)
{
    __shared__ int wsum[16];
    int tid = threadIdx.x, lane = tid & 63, wid = tid >> 6;
    int4 v = ((const int4*)cnt)[tid];
    int s0 = v.x, s1 = s0 + v.y, s2 = s1 + v.z, s3 = s2 + v.w;
    int q = s3;
#pragma unroll
    for (int o = 1; o < 64; o <<= 1) { int t = __shfl_up(q, o); if (lane >= o) q += t; }
    if (lane == 63) wsum[wid] = q;
    __syncthreads();
    if (wid == 0) {
        int w = (lane < 16) ? wsum[lane] : 0;
#pragma unroll
        for (int o = 1; o < 16; o <<= 1) { int t = __shfl_up(w, o); if (lane >= o) w += t; }
        if (lane < 16) wsum[lane] = w;
    }
    __syncthreads();
    int base = (wid ? wsum[wid - 1] : 0) + q - s3;
    int4 o4; o4.x = base; o4.y = base + s0; o4.z = base + s1; o4.w = base + s2;
    ((int4*)off)[tid] = o4;
    ((int4*)cur)[tid] = o4;
    if (tid == 1023) off[4096] = base + s3;
}

__launch_bounds__(256)
__global__ void bin_scatter_k(const int* __restrict__ ei, int E,
                              const int* __restrict__ map_idx,
                              int* __restrict__ bin_cur, unsigned* __restrict__ pairs,
                              int* __restrict__ pcnt, int* __restrict__ pnb)
{
    int e = blockIdx.x * blockDim.x + threadIdx.x;
    if (e >= E) return;
    int s = ei[e];
    int d = ei[E + e];
    int p = atomicAdd(&bin_cur[d >> 5], 1);
    pairs[p] = (unsigned)s | ((unsigned)(d & 31) << 27);
    int ms = map_idx[s];
    if (ms >= 0) {
        int i = atomicAdd(&pcnt[ms], 1);
        if (i < PSTRIDE) pnb[ms * PSTRIDE + i] = d;
    }
    int md = map_idx[d];
    if (md >= 0) {
        int i = atomicAdd(&pcnt[md], 1);
        if (i < PSTRIDE) pnb[md * PSTRIDE + i] = s;
    }
}

__launch_bounds__(256)
__global__ void bin_csr_k(const unsigned* __restrict__ pairs, const int* __restrict__ bin_off,
                          int* __restrict__ csr_in, int* __restrict__ in_off,
                          float* __restrict__ dis, int N)
{
    __shared__ int lcnt[32];
    __shared__ int lofs[32];
    __shared__ int lcur[32];
    int b = blockIdx.x;
    int tid = threadIdx.x;
    if (tid < 32) lcnt[tid] = 0;
    __syncthreads();
    int beg = bin_off[b], end = bin_off[b + 1];
    for (int i = beg + tid; i < end; i += 256)
        atomicAdd(&lcnt[pairs[i] >> 27], 1);
    __syncthreads();
    if (tid == 0) {
        int run = beg;
#pragma unroll
        for (int j = 0; j < 32; ++j) { lofs[j] = run; lcur[j] = run; run += lcnt[j]; }
    }
    __syncthreads();
    int n0 = b * 32;
    if (tid < 32 && n0 + tid < N) {
        in_off[n0 + tid] = lofs[tid];
        float dg = (float)lcnt[tid] + 1.0f;
        dis[n0 + tid] = rsqrtf(dg);
    }
    if (b == gridDim.x - 1 && tid == 0) in_off[N] = end;
    for (int i = beg + tid; i < end; i += 256) {
        unsigned pr = pairs[i];
        int p = atomicAdd(&lcur[pr >> 27], 1);
        csr_in[p] = (int)(pr & 0x07FFFFFFu);
    }
}

// Batched transpose + fp32->bf16: src [LAY][R][C] fp32 -> dst [LAY][C][R] bf16
__global__ void transpose_wb_k(const float* __restrict__ src, short* __restrict__ dst,
                               int LAY, int R, int Cc)
{
    int idx = blockIdx.x * blockDim.x + threadIdx.x;
    int tot = LAY * R * Cc;
    if (idx >= tot) return;
    int lay = idx / (R * Cc);
    int rem = idx - lay * R * Cc;
    int r = rem / Cc;
    int c = rem - r * Cc;
    dst[(size_t)lay * R * Cc + (size_t)c * R + r] = f2bf(src[idx]);
}

// ---------------------------------------------------------------------------
// Fused projector (MFMA, B-operands direct from global/L2):
// out(bf16) = dis[row] * (relu(LN(X@W1 + b1))@W2 + b2 [mix with last]).
// Block = 256 threads (4 waves in 2x2), tile = 128 rows x 128 cols.
// LDS: Xs[128][72] @0 (9216 sh, GEMM1) ; Hs[128][136] @0 (17408 sh, GEMM2,
// overlaps dead Xs) ; P floats @17408 (1024 sh). Total 36864 B -> 4 blk/CU.
// ---------------------------------------------------------------------------
__launch_bounds__(256, 4)
__global__ void proj_fused_k(const float* __restrict__ X,
                             const short* __restrict__ W1t,
                             const float* __restrict__ b1,
                             const float* __restrict__ lng,
                             const float* __restrict__ lnb,
                             const short* __restrict__ W2t,
                             const float* __restrict__ b2,
                             const float* __restrict__ alphas, int layer,
                             const float* __restrict__ last,
                             const float* __restrict__ dis,
                             short* __restrict__ out, int nrows)
{
    __shared__ short S[18432];

    const int tid  = threadIdx.x;
    const int lane = tid & 63;
    const int wave = tid >> 6;      // 0..3
    const int wr   = wave >> 1;     // row half
    const int wc   = wave & 1;      // col half
    const int g    = lane >> 4;
    const int lr   = lane & 15;
    const int row0 = blockIdx.x * 128;

    f32x4 acc[4][4];
#pragma unroll
    for (int fr = 0; fr < 4; ++fr)
#pragma unroll
        for (int fc = 0; fc < 4; ++fc) acc[fr][fc] = (f32x4){0.f, 0.f, 0.f, 0.f};

    // per-lane W bases (B-frag cols fixed per lane)
    const short* w1base[4];
#pragma unroll
    for (int fc = 0; fc < 4; ++fc)
        w1base[fc] = W1t + (size_t)(wc * 64 + fc * 16 + lr) * 1024 + g * 8;

    // ---------------- GEMM1: X[128,1024] @ W1[1024,128] ------------------
    const int xr   = tid >> 1;
    const int xc0  = (tid & 1) * 32;
    const bool xvalid = (row0 + xr) < nrows;
    const float* xbase = X + (size_t)(row0 + xr) * 1024 + xc0;

    for (int k0 = 0; k0 < 1024; k0 += 64) {
        // stage X tile (128 rows x 64 k) fp32->bf16
        {
            float4 v[8];
            if (xvalid) {
                const float* xp = xbase + k0;
#pragma unroll
                for (int m = 0; m < 8; ++m) v[m] = *(const float4*)&xp[m * 4];
            } else {
#pragma unroll
                for (int m = 0; m < 8; ++m) v[m] = make_float4(0.f, 0.f, 0.f, 0.f);
            }
#pragma unroll
            for (int m = 0; m < 4; ++m) {
                short8 p;
                p[0]=f2bf(v[2*m].x); p[1]=f2bf(v[2*m].y); p[2]=f2bf(v[2*m].z); p[3]=f2bf(v[2*m].w);
                p[4]=f2bf(v[2*m+1].x); p[5]=f2bf(v[2*m+1].y); p[6]=f2bf(v[2*m+1].z); p[7]=f2bf(v[2*m+1].w);
                *(short8*)&S[xr * 72 + xc0 + m * 8] = p;
            }
        }
        __syncthreads();
#pragma unroll
        for (int kk = 0; kk < 64; kk += 32) {
            short8 a[4], b[4];
#pragma unroll
            for (int fc = 0; fc < 4; ++fc)
                b[fc] = *(const short8*)&w1base[fc][k0 + kk];
#pragma unroll
            for (int fr = 0; fr < 4; ++fr)
                a[fr] = *(short8*)&S[(wr * 64 + fr * 16 + lr) * 72 + kk + g * 8];
#pragma unroll
            for (int fr = 0; fr < 4; ++fr)
#pragma unroll
                for (int fc = 0; fc < 4; ++fc)
                    acc[fr][fc] = __builtin_amdgcn_mfma_f32_16x16x32_bf16(a[fr], b[fc], acc[fr][fc], 0, 0, 0);
        }
        __syncthreads();
    }

    // ---------------- bias + LayerNorm(cross-wave) + ReLU -> Hs ----------
    float* P = (float*)&S[17408];   // [128][4]: s0,q0,s1,q1 per row
    {
        float b1v[4], gv[4], bv[4];
#pragma unroll
        for (int fc = 0; fc < 4; ++fc) {
            int col = wc * 64 + fc * 16 + lr;
            b1v[fc] = b1[col]; gv[fc] = lng[col]; bv[fc] = lnb[col];
        }
#pragma unroll
        for (int fr = 0; fr < 4; ++fr) {
#pragma unroll
            for (int j = 0; j < 4; ++j) {
                float s = 0.f, q = 0.f;
#pragma unroll
                for (int fc = 0; fc < 4; ++fc) {
                    float t = acc[fr][fc][j] + b1v[fc];
                    acc[fr][fc][j] = t;
                    s += t; q += t * t;
                }
#pragma unroll
                for (int m = 1; m < 16; m <<= 1) {
                    s += __shfl_xor(s, m);
                    q += __shfl_xor(q, m);
                }
                if (lr == 0) {
                    int row = wr * 64 + fr * 16 + 4 * g + j;
                    P[row * 4 + wc * 2]     = s;
                    P[row * 4 + wc * 2 + 1] = q;
                }
            }
        }
        __syncthreads();
#pragma unroll
        for (int fr = 0; fr < 4; ++fr) {
#pragma unroll
            for (int j = 0; j < 4; ++j) {
                int row = wr * 64 + fr * 16 + 4 * g + j;
                float s = P[row * 4 + 0] + P[row * 4 + 2];
                float q = P[row * 4 + 1] + P[row * 4 + 3];
                float mean = s * (1.0f / 128.0f);
                float var  = q * (1.0f / 128.0f) - mean * mean;
                float inv  = rsqrtf(var + 1e-5f);
#pragma unroll
                for (int fc = 0; fc < 4; ++fc) {
                    float h = fmaxf((acc[fr][fc][j] - mean) * inv * gv[fc] + bv[fc], 0.f);
                    S[row * 136 + wc * 64 + fc * 16 + lr] = f2bf(h);
                }
            }
        }
    }
    __syncthreads();   // Hs complete

    // ---------------- GEMM2: Hs[128,128] @ W2[128,128], W2 from L2 -------
    f32x4 acc2[4][4];
#pragma unroll
    for (int fr = 0; fr < 4; ++fr)
#pragma unroll
        for (int fc = 0; fc < 4; ++fc) acc2[fr][fc] = (f32x4){0.f, 0.f, 0.f, 0.f};

    const short* w2base[4];
#pragma unroll
    for (int fc = 0; fc < 4; ++fc)
        w2base[fc] = W2t + (size_t)(wc * 64 + fc * 16 + lr) * 128 + g * 8;

#pragma unroll
    for (int k0 = 0; k0 < 128; k0 += 32) {
        short8 a[4], b[4];
#pragma unroll
        for (int fc = 0; fc < 4; ++fc)
            b[fc] = *(const short8*)&w2base[fc][k0];
#pragma unroll
        for (int fr = 0; fr < 4; ++fr)
            a[fr] = *(short8*)&S[(wr * 64 + fr * 16 + lr) * 136 + k0 + g * 8];
#pragma unroll
        for (int fr = 0; fr < 4; ++fr)
#pragma unroll
            for (int fc = 0; fc < 4; ++fc)
                acc2[fr][fc] = __builtin_amdgcn_mfma_f32_16x16x32_bf16(a[fr], b[fc], acc2[fr][fc], 0, 0, 0);
    }

    // ---------------- epilogue: +b2, sigmoid-mix, dis-scale, store -------
    float b2v[4];
#pragma unroll
    for (int fc = 0; fc < 4; ++fc) b2v[fc] = b2[wc * 64 + fc * 16 + lr];
    float asig = 0.f, omas = 0.f;
    if (last) {
        float al = alphas[layer];
        asig = 1.0f / (1.0f + expf(-al * 10.0f));   // T = 0.1
        omas = 1.0f - asig;
    }
#pragma unroll
    for (int fr = 0; fr < 4; ++fr) {
#pragma unroll
        for (int j = 0; j < 4; ++j) {
            int gr = row0 + wr * 64 + fr * 16 + 4 * g + j;
            if (gr >= nrows) continue;
            float disr = dis[gr];
#pragma unroll
            for (int fc = 0; fc < 4; ++fc) {
                int col = wc * 64 + fc * 16 + lr;
                float o = acc2[fr][fc][j] + b2v[fc];
                if (last) o = asig * o + omas * last[(size_t)gr * 128 + col];
                out[(size_t)gr * 128 + col] = f2bf(o * disr);
            }
        }
    }
}

// ---------------------------------------------------------------------------
// Fused GCN MLP (MFMA, B direct from L2): V(bf16) = dis*(relu(U@gW1+gb1)@gW2)
// 64-row tile, 256 threads (4 waves). LDS: U[64][136]=8704 sh (phase A),
// Zs[64][264]=16896 sh (phase B, overlaps dead U). 33792 B -> 4 blk/CU.
// ---------------------------------------------------------------------------
__launch_bounds__(256, 4)
__global__ void gcn_mlp_k(const short* __restrict__ U,
                          const short* __restrict__ W1t,
                          const float* __restrict__ gb1,
                          const short* __restrict__ W2t,
                          const float* __restrict__ dis,
                          short* __restrict__ V, int M)
{
    __shared__ short S[16896];

    const int tid  = threadIdx.x;
    const int lane = tid & 63;
    const int wave = tid >> 6;
    const int g    = lane >> 4;
    const int lr   = lane & 15;
    const int m0   = blockIdx.x * 64;

    // stage U tile (64 x 128)
#pragma unroll
    for (int it = 0; it < 4; ++it) {
        int i = tid + it * 256;
        int r = i >> 4;
        int c8 = i & 15;
        short8 v = {0,0,0,0,0,0,0,0};
        int gr = m0 + r;
        if (gr < M) v = *(const short8*)&U[(size_t)gr * 128 + c8 * 8];
        *(short8*)&S[r * 136 + c8 * 8] = v;
    }
    __syncthreads();

    // phase A: z = relu(U @ W1 + b1); wave owns cols wave*64..+63
    f32x4 acc[4][4];
#pragma unroll
    for (int fr = 0; fr < 4; ++fr)
#pragma unroll
        for (int fc = 0; fc < 4; ++fc) acc[fr][fc] = (f32x4){0.f, 0.f, 0.f, 0.f};

    const short* w1base[4];
#pragma unroll
    for (int fc = 0; fc < 4; ++fc)
        w1base[fc] = W1t + (size_t)(wave * 64 + fc * 16 + lr) * 128 + g * 8;

#pragma unroll
    for (int k0 = 0; k0 < 128; k0 += 32) {
        short8 a[4], b[4];
#pragma unroll
        for (int fc = 0; fc < 4; ++fc)
            b[fc] = *(const short8*)&w1base[fc][k0];
#pragma unroll
        for (int fr = 0; fr < 4; ++fr)
            a[fr] = *(short8*)&S[(fr * 16 + lr) * 136 + k0 + g * 8];
#pragma unroll
        for (int fr = 0; fr < 4; ++fr)
#pragma unroll
            for (int fc = 0; fc < 4; ++fc)
                acc[fr][fc] = __builtin_amdgcn_mfma_f32_16x16x32_bf16(a[fr], b[fc], acc[fr][fc], 0, 0, 0);
    }
    __syncthreads();   // U dead; Zs region free

    // z -> Zs (bf16, stride 264)
    {
        float bb[4];
#pragma unroll
        for (int fc = 0; fc < 4; ++fc) bb[fc] = gb1[wave * 64 + fc * 16 + lr];
#pragma unroll
        for (int fr = 0; fr < 4; ++fr) {
#pragma unroll
            for (int j = 0; j < 4; ++j) {
                int rloc = fr * 16 + 4 * g + j;
#pragma unroll
                for (int fc = 0; fc < 4; ++fc) {
                    float zv = fmaxf(acc[fr][fc][j] + bb[fc], 0.f);
                    S[rloc * 264 + wave * 64 + fc * 16 + lr] = f2bf(zv);
                }
            }
        }
    }
    __syncthreads();   // Zs complete

    // phase B: V = Zs @ W2; wave owns cols wave*32..+31
    f32x4 acc2[4][2];
#pragma unroll
    for (int fr = 0; fr < 4; ++fr) {
        acc2[fr][0] = (f32x4){0.f, 0.f, 0.f, 0.f};
        acc2[fr][1] = (f32x4){0.f, 0.f, 0.f, 0.f};
    }

    const short* w2base[2];
#pragma unroll
    for (int fc = 0; fc < 2; ++fc)
        w2base[fc] = W2t + (size_t)(wave * 32 + fc * 16 + lr) * 256 + g * 8;

#pragma unroll
    for (int k0 = 0; k0 < 256; k0 += 32) {
        short8 a[4], b[2];
#pragma unroll
        for (int fc = 0; fc < 2; ++fc)
            b[fc] = *(const short8*)&w2base[fc][k0];
#pragma unroll
        for (int fr = 0; fr < 4; ++fr)
            a[fr] = *(short8*)&S[(fr * 16 + lr) * 264 + k0 + g * 8];
#pragma unroll
        for (int fr = 0; fr < 4; ++fr)
#pragma unroll
            for (int fc = 0; fc < 2; ++fc)
                acc2[fr][fc] = __builtin_amdgcn_mfma_f32_16x16x32_bf16(a[fr], b[fc], acc2[fr][fc], 0, 0, 0);
    }

#pragma unroll
    for (int fr = 0; fr < 4; ++fr) {
#pragma unroll
        for (int j = 0; j < 4; ++j) {
            int gr = m0 + fr * 16 + 4 * g + j;
            if (gr >= M) continue;
            float disr = dis[gr];
#pragma unroll
            for (int fc = 0; fc < 2; ++fc)
                V[(size_t)gr * 128 + wave * 32 + fc * 16 + lr] = f2bf(acc2[fr][fc][j] * disr);
        }
    }
}

// ---------------------------------------------------------------------------
// AGG (pre-scaled input): y[n] = dis[n]*(sum_{s in in(n)} x'[s] + x'[n]) (+bias)
// ---------------------------------------------------------------------------
template <bool OUT_BF16>
__launch_bounds__(256)
__global__ void agg_k(const unsigned* __restrict__ x, void* __restrict__ y,
                      const int* __restrict__ off, const int* __restrict__ csr,
                      const float* __restrict__ dis,
                      const float* __restrict__ bias, int N)
{
    int node = __builtin_amdgcn_readfirstlane(blockIdx.x * 4 + (threadIdx.x >> 6));
    if (node >= N) return;
    int lane = threadIdx.x & 63;
    int beg = off[node], end = off[node + 1];

    float ax0 = 0.f, ay0 = 0.f, ax1 = 0.f, ay1 = 0.f;
    float ax2 = 0.f, ay2 = 0.f, ax3 = 0.f, ay3 = 0.f;
    int e = beg;
    for (; e + 4 <= end; e += 4) {
        int s0 = csr[e], s1 = csr[e + 1], s2 = csr[e + 2], s3 = csr[e + 3];
        unsigned v0 = x[(size_t)s0 * 64 + lane];
        unsigned v1 = x[(size_t)s1 * 64 + lane];
        unsigned v2 = x[(size_t)s2 * 64 + lane];
        unsigned v3 = x[(size_t)s3 * 64 + lane];
        ax0 += __uint_as_float(v0 << 16);
        ay0 += __uint_as_float(v0 & 0xFFFF0000u);
        ax1 += __uint_as_float(v1 << 16);
        ay1 += __uint_as_float(v1 & 0xFFFF0000u);
        ax2 += __uint_as_float(v2 << 16);
        ay2 += __uint_as_float(v2 & 0xFFFF0000u);
        ax3 += __uint_as_float(v3 << 16);
        ay3 += __uint_as_float(v3 & 0xFFFF0000u);
    }
    for (; e < end; ++e) {
        int s = csr[e];
        unsigned v = x[(size_t)s * 64 + lane];
        ax0 += __uint_as_float(v << 16);
        ay0 += __uint_as_float(v & 0xFFFF0000u);
    }
    unsigned vo = x[(size_t)node * 64 + lane];
    float accx = ((ax0 + ax1) + (ax2 + ax3)) + __uint_as_float(vo << 16);
    float accy = ((ay0 + ay1) + (ay2 + ay3)) + __uint_as_float(vo & 0xFFFF0000u);

    float dn = dis[node];
    float rx = dn * accx;
    float ry = dn * accy;
    if (bias) { rx += bias[lane * 2]; ry += bias[lane * 2 + 1]; }
    if (OUT_BF16) {
        unsigned p = (unsigned)(unsigned short)f2bf(rx) | ((unsigned)(unsigned short)f2bf(ry) << 16);
        ((unsigned*)y)[(size_t)node * 64 + lane] = p;
    } else {
        *(float2*)&((float*)y)[(size_t)node * 128 + lane * 2] = make_float2(rx, ry);
    }
}

// ---------------------------------------------------------------------------
// Pooling (mapped nodes only, via pnb table) + classifier. last: fp32.
// ---------------------------------------------------------------------------
__launch_bounds__(128)
__global__ void pool_clf_k(const float* __restrict__ last, const int* __restrict__ mapping,
                           const int* __restrict__ map_idx,
                           const int* __restrict__ pcnt, const int* __restrict__ pnb,
                           const float* __restrict__ clfW, const float* __restrict__ clfb,
                           float* __restrict__ out, int C)
{
    int b = blockIdx.x;
    int tid = threadIdx.x;
    int n = mapping[b];
    int rep = map_idx[n];
    int cnt = pcnt[rep];
    int m = cnt < PSTRIDE ? cnt : PSTRIDE;

    float s = 0.f;
    const int* nb = pnb + (size_t)rep * PSTRIDE;
    for (int i = 0; i < m; ++i)
        s += last[(size_t)nb[i] * 128 + tid];

    float lv = last[(size_t)n * 128 + tid];
    float pooled = (lv + s) / (1.0f + (float)cnt);

    __shared__ float feat[256];
    feat[tid] = lv;
    feat[128 + tid] = pooled;
    __syncthreads();

    for (int c = tid; c < C; c += blockDim.x) {
        float o = clfb[c];
        for (int j = 0; j < 256; ++j) o = fmaf(feat[j], clfW[j * C + c], o);
        out[(size_t)b * C + c] = o;
    }
}

// ---------------------------------------------------------------------------
// Host launcher
// ---------------------------------------------------------------------------
extern "C" void kernel_launch(void* const* d_in, const int* in_sizes, int n_in,
                              void* d_out, int out_size, void* d_ws, size_t ws_size,
                              hipStream_t stream)
{
    const float* hidden = (const float*)d_in[0];
    const float* pW1    = (const float*)d_in[1];
    const float* pb1    = (const float*)d_in[2];
    const float* lng    = (const float*)d_in[3];
    const float* lnb    = (const float*)d_in[4];
    const float* pW2    = (const float*)d_in[5];
    const float* pb2    = (const float*)d_in[6];
    const float* alphas = (const float*)d_in[7];
    const float* gW1    = (const float*)d_in[8];
    const float* gb1    = (const float*)d_in[9];
    const float* gW2    = (const float*)d_in[10];
    const float* gb2    = (const float*)d_in[11];
    const float* clfW   = (const float*)d_in[12];
    const float* clfb   = (const float*)d_in[13];
    const int*   ei     = (const int*)d_in[14];
    const int*   mapping= (const int*)d_in[15];

    const int L   = in_sizes[7];                 // 2
    const int K   = in_sizes[2] / L;             // 128
    const int H   = in_sizes[9] / L;             // 256
    const int C   = in_sizes[13];                // 40
    const int DLM = in_sizes[1] / (L * K);       // 1024
    const int N   = in_sizes[0] / (L * DLM);     // 100000
    const int E   = in_sizes[14] / 2;            // 3200000
    const int B   = in_sizes[15];                // 1024
    const int NBINS = (N + 31) / 32;             // 3125 (<= 4096)

    char* ws = (char*)d_ws;
    size_t off = 0;
    auto carve = [&](size_t bytes) -> char* {
        char* p = ws + off;
        off += (bytes + 255) & ~(size_t)255;
        return p;
    };
    int*      map_idx = (int*)carve((size_t)N * 4);
    int*      pcnt    = (int*)carve((size_t)B * 4);
    int*      pnb     = (int*)carve((size_t)B * PSTRIDE * 4);
    int*      bin_cnt = (int*)carve(4096 * 4);
    int*      bin_off = (int*)carve(4097 * 4);
    int*      bin_cur = (int*)carve(4096 * 4);
    unsigned* pairs   = (unsigned*)carve((size_t)E * 4);
    int*      in_off  = (int*)carve((size_t)(N + 1) * 4);
    float*    dis     = (float*)carve((size_t)N * 4);
    int*      csr_in  = (int*)carve((size_t)E * 4);
    short*    bufA    = (short*)carve((size_t)N * K * 2);    // h' / v' (bf16, dis-scaled)
    short*    bufU    = (short*)carve((size_t)N * K * 2);    // u (bf16)
    float*    bufLast = (float*)carve((size_t)N * K * 4);    // last (fp32)
    short*    w1t     = (short*)carve((size_t)L * K * DLM * 2);
    short*    w2t     = (short*)carve((size_t)L * K * K * 2);
    short*    gw1t    = (short*)carve((size_t)L * H * K * 2);  // [L][256][128]
    short*    gw2t    = (short*)carve((size_t)L * K * H * 2);  // [L][128][256]
    (void)ws_size; (void)n_in; (void)out_size;

    // graph prep
    hipMemsetAsync(bin_cnt, 0, 4096 * 4, stream);
    hipMemsetAsync(map_idx, 0xFF, (size_t)N * 4, stream);
    hipMemsetAsync(pcnt, 0, (size_t)B * 4, stream);
    map_scatter_k<<<dim3((B + 255) / 256), 256, 0, stream>>>(mapping, map_idx, B);
    bin_count_k<<<dim3((E + 32767) / 32768), 1024, 0, stream>>>(ei + E, E, bin_cnt);
    scan_bins_k<<<dim3(1), 1024, 0, stream>>>(bin_cnt, bin_off, bin_cur);
    bin_scatter_k<<<dim3((E + 255) / 256), 256, 0, stream>>>(ei, E, map_idx, bin_cur,
                                                             pairs, pcnt, pnb);
    bin_csr_k<<<dim3(NBINS), 256, 0, stream>>>(pairs, bin_off, csr_in, in_off,
                                               dis, N);

    // weight transpose + bf16 convert (batched over layers)
    transpose_wb_k<<<dim3((L * DLM * K + 255) / 256), 256, 0, stream>>>(pW1, w1t, L, DLM, K);
    transpose_wb_k<<<dim3((L * K * K + 255) / 256), 256, 0, stream>>>(pW2, w2t, L, K, K);
    transpose_wb_k<<<dim3((L * K * H + 255) / 256), 256, 0, stream>>>(gW1, gw1t, L, K, H);
    transpose_wb_k<<<dim3((L * H * K + 255) / 256), 256, 0, stream>>>(gW2, gw2t, L, H, K);

    const int nblk64  = (N + 63) / 64;
    const int nblk128 = (N + 127) / 128;

    // layers
    for (int i = 0; i < L; ++i) {
        proj_fused_k<<<dim3(nblk128), 256, 0, stream>>>(
            hidden + (size_t)i * N * DLM,
            w1t + (size_t)i * K * DLM,
            pb1 + (size_t)i * K,
            lng + (size_t)i * K,
            lnb + (size_t)i * K,
            w2t + (size_t)i * K * K,
            pb2 + (size_t)i * K,
            alphas, i,
            (i > 0) ? bufLast : nullptr,
            dis,
            bufA, N);

        // u = A_hat-normalized sum of pre-scaled h'   (bf16 -> bf16)
        agg_k<true><<<dim3((N + 3) / 4), 256, 0, stream>>>(
            (const unsigned*)bufA, bufU, in_off, csr_in, dis, nullptr, N);
        // v' = dis * (relu(u @ gW1 + gb1) @ gW2)   (fused, z in LDS)
        gcn_mlp_k<<<dim3(nblk64), 256, 0, stream>>>(
            bufU, gw1t + (size_t)i * H * K, gb1 + (size_t)i * H,
            gw2t + (size_t)i * K * H, dis, bufA, N);
        // last = A_hat-normalized sum of v' + gb2   (bf16 -> fp32)
        agg_k<false><<<dim3((N + 3) / 4), 256, 0, stream>>>(
            (const unsigned*)bufA, bufLast, in_off, csr_in, dis,
            gb2 + (size_t)i * K, N);
    }

    // pooling + classifier
    pool_clf_k<<<dim3(B), 128, 0, stream>>>(bufLast, mapping, map_idx, pcnt, pnb,
                                            clfW, clfb, (float*)d_out, C);
}

// Round 11
// 1206.311 us; speedup vs baseline: 1.0352x; 1.0352x over previous
//
#include <hip/hip_runtime.h>
#include <hip/hip_bf16.h>
#include <math.h>

using short8 = __attribute__((ext_vector_type(8))) short;
using f32x4  = __attribute__((ext_vector_type(4))) float;

#define PSTRIDE 2048   // per-batch neighbor table stride

__device__ __forceinline__ short f2bf(float f) {
    __hip_bfloat16 h = __float2bfloat16(f);   // RNE; pairs fuse to v_cvt_pk_bf16_f32
    return *reinterpret_cast<short*>(&h);
}
__device__ __forceinline__ float bf2f(unsigned short u) {
    return __uint_as_float(((unsigned)u) << 16);
}

// ---------------------------------------------------------------------------
// Graph prep: binned CSR build (dst-binned, 32 nodes per bin)
// pairs entry packed: s (bits 0..16) | (d&31)<<27
// ---------------------------------------------------------------------------

__global__ void map_scatter_k(const int* __restrict__ mapping, int* __restrict__ map_idx, int B)
{
    int b = blockIdx.x * blockDim.x + threadIdx.x;
    if (b < B) map_idx[mapping[b]] = b;
}

__launch_bounds__(1024)
__global__ void bin_count_k(const int* __restrict__ dst, int E, int* __restrict__ bin_cnt)
{
    __shared__ int h[4096];
    for (int i = threadIdx.x; i < 4096; i += 1024) h[i] = 0;
    __syncthreads();
    int base = blockIdx.x * 32768;
#pragma unroll
    for (int i = 0; i < 32; ++i) {
        int e = base + i * 1024 + threadIdx.x;
        if (e < E) atomicAdd(&h[dst[e] >> 5], 1);
    }
    __syncthreads();
    for (int i = threadIdx.x; i < 4096; i += 1024) {
        int c = h[i];
        if (c) atomicAdd(&bin_cnt[i], c);
    }
}

__launch_bounds__(1024)
__global__ void scan_bins_k(const int* __restrict__ cnt, int* __restrict__ off,
                            int* __restrict__ cur)
{
    __shared__ int wsum[16];
    int tid = threadIdx.x, lane = tid & 63, wid = tid >> 6;
    int4 v = ((const int4*)cnt)[tid];
    int s0 = v.x, s1 = s0 + v.y, s2 = s1 + v.z, s3 = s2 + v.w;
    int q = s3;
#pragma unroll
    for (int o = 1; o < 64; o <<= 1) { int t = __shfl_up(q, o); if (lane >= o) q += t; }
    if (lane == 63) wsum[wid] = q;
    __syncthreads();
    if (wid == 0) {
        int w = (lane < 16) ? wsum[lane] : 0;
#pragma unroll
        for (int o = 1; o < 16; o <<= 1) { int t = __shfl_up(w, o); if (lane >= o) w += t; }
        if (lane < 16) wsum[lane] = w;
    }
    __syncthreads();
    int base = (wid ? wsum[wid - 1] : 0) + q - s3;
    int4 o4; o4.x = base; o4.y = base + s0; o4.z = base + s1; o4.w = base + s2;
    ((int4*)off)[tid] = o4;
    ((int4*)cur)[tid] = o4;
    if (tid == 1023) off[4096] = base + s3;
}

__launch_bounds__(256)
__global__ void bin_scatter_k(const int* __restrict__ ei, int E,
                              const int* __restrict__ map_idx,
                              int* __restrict__ bin_cur, unsigned* __restrict__ pairs,
                              int* __restrict__ pcnt, int* __restrict__ pnb)
{
    int e = blockIdx.x * blockDim.x + threadIdx.x;
    if (e >= E) return;
    int s = ei[e];
    int d = ei[E + e];
    int p = atomicAdd(&bin_cur[d >> 5], 1);
    pairs[p] = (unsigned)s | ((unsigned)(d & 31) << 27);
    int ms = map_idx[s];
    if (ms >= 0) {
        int i = atomicAdd(&pcnt[ms], 1);
        if (i < PSTRIDE) pnb[ms * PSTRIDE + i] = d;
    }
    int md = map_idx[d];
    if (md >= 0) {
        int i = atomicAdd(&pcnt[md], 1);
        if (i < PSTRIDE) pnb[md * PSTRIDE + i] = s;
    }
}

__launch_bounds__(256)
__global__ void bin_csr_k(const unsigned* __restrict__ pairs, const int* __restrict__ bin_off,
                          int* __restrict__ csr_in, int* __restrict__ in_off,
                          float* __restrict__ dis, int N)
{
    __shared__ int lcnt[32];
    __shared__ int lofs[32];
    __shared__ int lcur[32];
    int b = blockIdx.x;
    int tid = threadIdx.x;
    if (tid < 32) lcnt[tid] = 0;
    __syncthreads();
    int beg = bin_off[b], end = bin_off[b + 1];
    for (int i = beg + tid; i < end; i += 256)
        atomicAdd(&lcnt[pairs[i] >> 27], 1);
    __syncthreads();
    if (tid == 0) {
        int run = beg;
#pragma unroll
        for (int j = 0; j < 32; ++j) { lofs[j] = run; lcur[j] = run; run += lcnt[j]; }
    }
    __syncthreads();
    int n0 = b * 32;
    if (tid < 32 && n0 + tid < N) {
        in_off[n0 + tid] = lofs[tid];
        float dg = (float)lcnt[tid] + 1.0f;
        dis[n0 + tid] = rsqrtf(dg);
    }
    if (b == gridDim.x - 1 && tid == 0) in_off[N] = end;
    for (int i = beg + tid; i < end; i += 256) {
        unsigned pr = pairs[i];
        int p = atomicAdd(&lcur[pr >> 27], 1);
        csr_in[p] = (int)(pr & 0x07FFFFFFu);
    }
}

// Batched transpose + fp32->bf16: src [LAY][R][C] fp32 -> dst [LAY][C][R] bf16
__global__ void transpose_wb_k(const float* __restrict__ src, short* __restrict__ dst,
                               int LAY, int R, int Cc)
{
    int idx = blockIdx.x * blockDim.x + threadIdx.x;
    int tot = LAY * R * Cc;
    if (idx >= tot) return;
    int lay = idx / (R * Cc);
    int rem = idx - lay * R * Cc;
    int r = rem / Cc;
    int c = rem - r * Cc;
    dst[(size_t)lay * R * Cc + (size_t)c * R + r] = f2bf(src[idx]);
}

// ---------------------------------------------------------------------------
// Fused projector (MFMA, software-pipelined staging) — R9 structure:
// out(bf16) = dis[row] * (relu(LN(X@W1 + b1))@W2 + b2 [mix with bf16 last]).
// Block = 256 threads (4 waves in 2x2), tile = 128 rows x 128 cols.
// ---------------------------------------------------------------------------
__launch_bounds__(256)
__global__ void proj_fused_k(const float* __restrict__ X,
                             const short* __restrict__ W1t,
                             const float* __restrict__ b1,
                             const float* __restrict__ lng,
                             const float* __restrict__ lnb,
                             const short* __restrict__ W2t,
                             const float* __restrict__ b2,
                             const float* __restrict__ alphas, int layer,
                             const unsigned short* __restrict__ last,
                             const float* __restrict__ dis,
                             short* __restrict__ out, int nrows)
{
    __shared__ short S[26624];

    const int tid  = threadIdx.x;
    const int lane = tid & 63;
    const int wave = tid >> 6;      // 0..3
    const int wr   = wave >> 1;     // row half
    const int wc   = wave & 1;      // col half
    const int g    = lane >> 4;
    const int lr   = lane & 15;
    const int row0 = blockIdx.x * 128;

    f32x4 acc[4][4];
#pragma unroll
    for (int fr = 0; fr < 4; ++fr)
#pragma unroll
        for (int fc = 0; fc < 4; ++fc) acc[fr][fc] = (f32x4){0.f, 0.f, 0.f, 0.f};

    // ---------------- GEMM1: X[128,1024] @ W1[1024,128], pipelined -------
    const int xr   = tid >> 1;
    const int xc0  = (tid & 1) * 32;
    const bool xvalid = (row0 + xr) < nrows;
    const float* xbase = X + (size_t)(row0 + xr) * 1024 + xc0;
    const short* wbase = W1t + (size_t)(tid >> 1) * 1024 + (tid & 1) * 32;

    float4 xv[8];
    short8 wv[4];
    if (xvalid) {
#pragma unroll
        for (int m = 0; m < 8; ++m) xv[m] = *(const float4*)&xbase[m * 4];
    } else {
#pragma unroll
        for (int m = 0; m < 8; ++m) xv[m] = make_float4(0.f, 0.f, 0.f, 0.f);
    }
#pragma unroll
    for (int m = 0; m < 4; ++m) wv[m] = *(const short8*)&wbase[m * 8];

    for (int k0 = 0; k0 < 1024; k0 += 64) {
#pragma unroll
        for (int m = 0; m < 4; ++m) {
            short8 p;
            p[0]=f2bf(xv[2*m].x); p[1]=f2bf(xv[2*m].y); p[2]=f2bf(xv[2*m].z); p[3]=f2bf(xv[2*m].w);
            p[4]=f2bf(xv[2*m+1].x); p[5]=f2bf(xv[2*m+1].y); p[6]=f2bf(xv[2*m+1].z); p[7]=f2bf(xv[2*m+1].w);
            *(short8*)&S[xr * 72 + xc0 + m * 8] = p;
        }
#pragma unroll
        for (int m = 0; m < 4; ++m)
            *(short8*)&S[9216 + (tid >> 1) * 72 + (tid & 1) * 32 + m * 8] = wv[m];
        __syncthreads();

        if (k0 + 64 < 1024) {
            if (xvalid) {
                const float* xp = xbase + k0 + 64;
#pragma unroll
                for (int m = 0; m < 8; ++m) xv[m] = *(const float4*)&xp[m * 4];
            }
            const short* wp = wbase + k0 + 64;
#pragma unroll
            for (int m = 0; m < 4; ++m) wv[m] = *(const short8*)&wp[m * 8];
        }

#pragma unroll
        for (int kk = 0; kk < 64; kk += 32) {
            short8 a[4], b[4];
#pragma unroll
            for (int fr = 0; fr < 4; ++fr)
                a[fr] = *(short8*)&S[(wr * 64 + fr * 16 + lr) * 72 + kk + g * 8];
#pragma unroll
            for (int fc = 0; fc < 4; ++fc)
                b[fc] = *(short8*)&S[9216 + (wc * 64 + fc * 16 + lr) * 72 + kk + g * 8];
#pragma unroll
            for (int fr = 0; fr < 4; ++fr)
#pragma unroll
                for (int fc = 0; fc < 4; ++fc)
                    acc[fr][fc] = __builtin_amdgcn_mfma_f32_16x16x32_bf16(a[fr], b[fc], acc[fr][fc], 0, 0, 0);
        }
        __syncthreads();
    }

    // ---------------- bias + LayerNorm(cross-wave) + ReLU -> Hs ----------
    float* P = (float*)&S[17408];   // [128][4]: s0,q0,s1,q1 per row
    {
        float b1v[4], gv[4], bv[4];
#pragma unroll
        for (int fc = 0; fc < 4; ++fc) {
            int col = wc * 64 + fc * 16 + lr;
            b1v[fc] = b1[col]; gv[fc] = lng[col]; bv[fc] = lnb[col];
        }
#pragma unroll
        for (int fr = 0; fr < 4; ++fr) {
#pragma unroll
            for (int j = 0; j < 4; ++j) {
                float s = 0.f, q = 0.f;
#pragma unroll
                for (int fc = 0; fc < 4; ++fc) {
                    float t = acc[fr][fc][j] + b1v[fc];
                    acc[fr][fc][j] = t;
                    s += t; q += t * t;
                }
#pragma unroll
                for (int m = 1; m < 16; m <<= 1) {
                    s += __shfl_xor(s, m);
                    q += __shfl_xor(q, m);
                }
                if (lr == 0) {
                    int row = wr * 64 + fr * 16 + 4 * g + j;
                    P[row * 4 + wc * 2]     = s;
                    P[row * 4 + wc * 2 + 1] = q;
                }
            }
        }
        __syncthreads();
#pragma unroll
        for (int fr = 0; fr < 4; ++fr) {
#pragma unroll
            for (int j = 0; j < 4; ++j) {
                int row = wr * 64 + fr * 16 + 4 * g + j;
                float s = P[row * 4 + 0] + P[row * 4 + 2];
                float q = P[row * 4 + 1] + P[row * 4 + 3];
                float mean = s * (1.0f / 128.0f);
                float var  = q * (1.0f / 128.0f) - mean * mean;
                float inv  = rsqrtf(var + 1e-5f);
#pragma unroll
                for (int fc = 0; fc < 4; ++fc) {
                    float h = fmaxf((acc[fr][fc][j] - mean) * inv * gv[fc] + bv[fc], 0.f);
                    S[row * 136 + wc * 64 + fc * 16 + lr] = f2bf(h);
                }
            }
        }
    }
    __syncthreads();

    // ---------------- GEMM2: Hs[128,128] @ W2[128,128] -------------------
    f32x4 acc2[4][4];
#pragma unroll
    for (int fr = 0; fr < 4; ++fr)
#pragma unroll
        for (int fc = 0; fc < 4; ++fc) acc2[fr][fc] = (f32x4){0.f, 0.f, 0.f, 0.f};

    for (int k0 = 0; k0 < 128; k0 += 64) {
        {
            int c  = tid >> 1;
            int kb = (tid & 1) * 32;
            const short* wp = W2t + (size_t)c * 128 + k0 + kb;
#pragma unroll
            for (int m = 0; m < 4; ++m)
                *(short8*)&S[17408 + c * 72 + kb + m * 8] = *(const short8*)&wp[m * 8];
        }
        __syncthreads();
#pragma unroll
        for (int kk = 0; kk < 64; kk += 32) {
            short8 a[4], b[4];
#pragma unroll
            for (int fr = 0; fr < 4; ++fr)
                a[fr] = *(short8*)&S[(wr * 64 + fr * 16 + lr) * 136 + k0 + kk + g * 8];
#pragma unroll
            for (int fc = 0; fc < 4; ++fc)
                b[fc] = *(short8*)&S[17408 + (wc * 64 + fc * 16 + lr) * 72 + kk + g * 8];
#pragma unroll
            for (int fr = 0; fr < 4; ++fr)
#pragma unroll
                for (int fc = 0; fc < 4; ++fc)
                    acc2[fr][fc] = __builtin_amdgcn_mfma_f32_16x16x32_bf16(a[fr], b[fc], acc2[fr][fc], 0, 0, 0);
        }
        __syncthreads();
    }

    // ---------------- epilogue: +b2, sigmoid-mix, dis-scale, store -------
    float b2v[4];
#pragma unroll
    for (int fc = 0; fc < 4; ++fc) b2v[fc] = b2[wc * 64 + fc * 16 + lr];
    float asig = 0.f, omas = 0.f;
    if (last) {
        float al = alphas[layer];
        asig = 1.0f / (1.0f + expf(-al * 10.0f));   // T = 0.1
        omas = 1.0f - asig;
    }
#pragma unroll
    for (int fr = 0; fr < 4; ++fr) {
#pragma unroll
        for (int j = 0; j < 4; ++j) {
            int gr = row0 + wr * 64 + fr * 16 + 4 * g + j;
            if (gr >= nrows) continue;
            float disr = dis[gr];
#pragma unroll
            for (int fc = 0; fc < 4; ++fc) {
                int col = wc * 64 + fc * 16 + lr;
                float o = acc2[fr][fc][j] + b2v[fc];
                if (last) o = asig * o + omas * bf2f(last[(size_t)gr * 128 + col]);
                out[(size_t)gr * 128 + col] = f2bf(o * disr);
            }
        }
    }
}

// ---------------------------------------------------------------------------
// Fused GCN MLP (MFMA) — R9 structure: V(bf16) = dis*(relu(U@gW1+gb1)@gW2)
// ---------------------------------------------------------------------------
__launch_bounds__(256)
__global__ void gcn_mlp_k(const short* __restrict__ U,
                          const short* __restrict__ W1t,
                          const float* __restrict__ gb1,
                          const short* __restrict__ W2t,
                          const float* __restrict__ dis,
                          short* __restrict__ V, int M)
{
    __shared__ short S[35840];

    const int tid  = threadIdx.x;
    const int lane = tid & 63;
    const int wave = tid >> 6;
    const int g    = lane >> 4;
    const int lr   = lane & 15;
    const int m0   = blockIdx.x * 64;

    // stage U tile (64 x 128)
#pragma unroll
    for (int it = 0; it < 4; ++it) {
        int i = tid + it * 256;
        int r = i >> 4;
        int c8 = i & 15;
        short8 v = {0,0,0,0,0,0,0,0};
        int gr = m0 + r;
        if (gr < M) v = *(const short8*)&U[(size_t)gr * 128 + c8 * 8];
        *(short8*)&S[r * 136 + c8 * 8] = v;
    }

    // phase A: z = relu(U @ W1 + b1); wave owns cols wave*64..+63
    f32x4 acc[4][4];
#pragma unroll
    for (int fr = 0; fr < 4; ++fr)
#pragma unroll
        for (int fc = 0; fc < 4; ++fc) acc[fr][fc] = (f32x4){0.f, 0.f, 0.f, 0.f};

    for (int k0 = 0; k0 < 128; k0 += 64) {
#pragma unroll
        for (int it = 0; it < 8; ++it) {
            int i = tid + it * 256;
            int r = i >> 3;
            int c8 = i & 7;
            *(short8*)&S[17408 + r * 72 + c8 * 8] =
                *(const short8*)&W1t[(size_t)r * 128 + k0 + c8 * 8];
        }
        __syncthreads();
#pragma unroll
        for (int kk = 0; kk < 64; kk += 32) {
            short8 a[4], b[4];
#pragma unroll
            for (int fr = 0; fr < 4; ++fr)
                a[fr] = *(short8*)&S[(fr * 16 + lr) * 136 + k0 + kk + g * 8];
#pragma unroll
            for (int fc = 0; fc < 4; ++fc)
                b[fc] = *(short8*)&S[17408 + (wave * 64 + fc * 16 + lr) * 72 + kk + g * 8];
#pragma unroll
            for (int fr = 0; fr < 4; ++fr)
#pragma unroll
                for (int fc = 0; fc < 4; ++fc)
                    acc[fr][fc] = __builtin_amdgcn_mfma_f32_16x16x32_bf16(a[fr], b[fc], acc[fr][fc], 0, 0, 0);
        }
        __syncthreads();
    }

    // z -> Zs (bf16, stride 264)
    {
        float bb[4];
#pragma unroll
        for (int fc = 0; fc < 4; ++fc) bb[fc] = gb1[wave * 64 + fc * 16 + lr];
#pragma unroll
        for (int fr = 0; fr < 4; ++fr) {
#pragma unroll
            for (int j = 0; j < 4; ++j) {
                int rloc = fr * 16 + 4 * g + j;
#pragma unroll
                for (int fc = 0; fc < 4; ++fc) {
                    float zv = fmaxf(acc[fr][fc][j] + bb[fc], 0.f);
                    S[rloc * 264 + wave * 64 + fc * 16 + lr] = f2bf(zv);
                }
            }
        }
    }

    // phase B: V = Zs @ W2; wave owns cols wave*32..+31
    f32x4 acc2[4][2];
#pragma unroll
    for (int fr = 0; fr < 4; ++fr) {
        acc2[fr][0] = (f32x4){0.f, 0.f, 0.f, 0.f};
        acc2[fr][1] = (f32x4){0.f, 0.f, 0.f, 0.f};
    }

    for (int k0 = 0; k0 < 256; k0 += 64) {
#pragma unroll
        for (int it = 0; it < 4; ++it) {
            int i = tid + it * 256;
            int r = i >> 3;
            int c8 = i & 7;
            *(short8*)&S[16896 + r * 72 + c8 * 8] =
                *(const short8*)&W2t[(size_t)r * 256 + k0 + c8 * 8];
        }
        __syncthreads();
#pragma unroll
        for (int kk = 0; kk < 64; kk += 32) {
            short8 a[4], b[2];
#pragma unroll
            for (int fr = 0; fr < 4; ++fr)
                a[fr] = *(short8*)&S[(fr * 16 + lr) * 264 + k0 + kk + g * 8];
#pragma unroll
            for (int fc = 0; fc < 2; ++fc)
                b[fc] = *(short8*)&S[16896 + (wave * 32 + fc * 16 + lr) * 72 + kk + g * 8];
#pragma unroll
            for (int fr = 0; fr < 4; ++fr)
#pragma unroll
                for (int fc = 0; fc < 2; ++fc)
                    acc2[fr][fc] = __builtin_amdgcn_mfma_f32_16x16x32_bf16(a[fr], b[fc], acc2[fr][fc], 0, 0, 0);
        }
        __syncthreads();
    }

#pragma unroll
    for (int fr = 0; fr < 4; ++fr) {
#pragma unroll
        for (int j = 0; j < 4; ++j) {
            int gr = m0 + fr * 16 + 4 * g + j;
            if (gr >= M) continue;
            float disr = dis[gr];
#pragma unroll
            for (int fc = 0; fc < 2; ++fc)
                V[(size_t)gr * 128 + wave * 32 + fc * 16 + lr] = f2bf(acc2[fr][fc][j] * disr);
        }
    }
}

// ---------------------------------------------------------------------------
// AGG (pre-scaled input): y(bf16)[n] = dis[n]*(sum x'[s] + x'[n]) (+bias)
// ---------------------------------------------------------------------------
__launch_bounds__(256)
__global__ void agg_k(const unsigned* __restrict__ x, unsigned* __restrict__ y,
                      const int* __restrict__ off, const int* __restrict__ csr,
                      const float* __restrict__ dis,
                      const float* __restrict__ bias, int N)
{
    int node = __builtin_amdgcn_readfirstlane(blockIdx.x * 4 + (threadIdx.x >> 6));
    if (node >= N) return;
    int lane = threadIdx.x & 63;
    int beg = off[node], end = off[node + 1];

    float ax0 = 0.f, ay0 = 0.f, ax1 = 0.f, ay1 = 0.f;
    float ax2 = 0.f, ay2 = 0.f, ax3 = 0.f, ay3 = 0.f;
    int e = beg;
    for (; e + 4 <= end; e += 4) {
        int s0 = csr[e], s1 = csr[e + 1], s2 = csr[e + 2], s3 = csr[e + 3];
        unsigned v0 = x[(size_t)s0 * 64 + lane];
        unsigned v1 = x[(size_t)s1 * 64 + lane];
        unsigned v2 = x[(size_t)s2 * 64 + lane];
        unsigned v3 = x[(size_t)s3 * 64 + lane];
        ax0 += __uint_as_float(v0 << 16);
        ay0 += __uint_as_float(v0 & 0xFFFF0000u);
        ax1 += __uint_as_float(v1 << 16);
        ay1 += __uint_as_float(v1 & 0xFFFF0000u);
        ax2 += __uint_as_float(v2 << 16);
        ay2 += __uint_as_float(v2 & 0xFFFF0000u);
        ax3 += __uint_as_float(v3 << 16);
        ay3 += __uint_as_float(v3 & 0xFFFF0000u);
    }
    for (; e < end; ++e) {
        int s = csr[e];
        unsigned v = x[(size_t)s * 64 + lane];
        ax0 += __uint_as_float(v << 16);
        ay0 += __uint_as_float(v & 0xFFFF0000u);
    }
    unsigned vo = x[(size_t)node * 64 + lane];
    float accx = ((ax0 + ax1) + (ax2 + ax3)) + __uint_as_float(vo << 16);
    float accy = ((ay0 + ay1) + (ay2 + ay3)) + __uint_as_float(vo & 0xFFFF0000u);

    float dn = dis[node];
    float rx = dn * accx;
    float ry = dn * accy;
    if (bias) { rx += bias[lane * 2]; ry += bias[lane * 2 + 1]; }
    unsigned p = (unsigned)(unsigned short)f2bf(rx) | ((unsigned)(unsigned short)f2bf(ry) << 16);
    y[(size_t)node * 64 + lane] = p;
}

// ---------------------------------------------------------------------------
// Pooling (mapped nodes only, via pnb table) + classifier. last: bf16.
// ---------------------------------------------------------------------------
__launch_bounds__(128)
__global__ void pool_clf_k(const unsigned short* __restrict__ last,
                           const int* __restrict__ mapping,
                           const int* __restrict__ map_idx,
                           const int* __restrict__ pcnt, const int* __restrict__ pnb,
                           const float* __restrict__ clfW, const float* __restrict__ clfb,
                           float* __restrict__ out, int C)
{
    int b = blockIdx.x;
    int tid = threadIdx.x;
    int n = mapping[b];
    int rep = map_idx[n];
    int cnt = pcnt[rep];
    int m = cnt < PSTRIDE ? cnt : PSTRIDE;

    float s = 0.f;
    const int* nb = pnb + (size_t)rep * PSTRIDE;
    for (int i = 0; i < m; ++i)
        s += bf2f(last[(size_t)nb[i] * 128 + tid]);

    float lv = bf2f(last[(size_t)n * 128 + tid]);
    float pooled = (lv + s) / (1.0f + (float)cnt);

    __shared__ float feat[256];
    feat[tid] = lv;
    feat[128 + tid] = pooled;
    __syncthreads();

    for (int c = tid; c < C; c += blockDim.x) {
        float o = clfb[c];
        for (int j = 0; j < 256; ++j) o = fmaf(feat[j], clfW[j * C + c], o);
        out[(size_t)b * C + c] = o;
    }
}

// ---------------------------------------------------------------------------
// Host launcher
// ---------------------------------------------------------------------------
extern "C" void kernel_launch(void* const* d_in, const int* in_sizes, int n_in,
                              void* d_out, int out_size, void* d_ws, size_t ws_size,
                              hipStream_t stream)
{
    const float* hidden = (const float*)d_in[0];
    const float* pW1    = (const float*)d_in[1];
    const float* pb1    = (const float*)d_in[2];
    const float* lng    = (const float*)d_in[3];
    const float* lnb    = (const float*)d_in[4];
    const float* pW2    = (const float*)d_in[5];
    const float* pb2    = (const float*)d_in[6];
    const float* alphas = (const float*)d_in[7];
    const float* gW1    = (const float*)d_in[8];
    const float* gb1    = (const float*)d_in[9];
    const float* gW2    = (const float*)d_in[10];
    const float* gb2    = (const float*)d_in[11];
    const float* clfW   = (const float*)d_in[12];
    const float* clfb   = (const float*)d_in[13];
    const int*   ei     = (const int*)d_in[14];
    const int*   mapping= (const int*)d_in[15];

    const int L   = in_sizes[7];                 // 2
    const int K   = in_sizes[2] / L;             // 128
    const int H   = in_sizes[9] / L;             // 256
    const int C   = in_sizes[13];                // 40
    const int DLM = in_sizes[1] / (L * K);       // 1024
    const int N   = in_sizes[0] / (L * DLM);     // 100000
    const int E   = in_sizes[14] / 2;            // 3200000
    const int B   = in_sizes[15];                // 1024
    const int NBINS = (N + 31) / 32;             // 3125 (<= 4096)

    char* ws = (char*)d_ws;
    size_t off = 0;
    auto carve = [&](size_t bytes) -> char* {
        char* p = ws + off;
        off += (bytes + 255) & ~(size_t)255;
        return p;
    };
    int*      map_idx = (int*)carve((size_t)N * 4);
    int*      pcnt    = (int*)carve((size_t)B * 4);
    int*      pnb     = (int*)carve((size_t)B * PSTRIDE * 4);
    int*      bin_cnt = (int*)carve(4096 * 4);
    int*      bin_off = (int*)carve(4097 * 4);
    int*      bin_cur = (int*)carve(4096 * 4);
    unsigned* pairs   = (unsigned*)carve((size_t)E * 4);
    int*      in_off  = (int*)carve((size_t)(N + 1) * 4);
    float*    dis     = (float*)carve((size_t)N * 4);
    int*      csr_in  = (int*)carve((size_t)E * 4);
    short*    bufA    = (short*)carve((size_t)N * K * 2);    // h' / v' (bf16, dis-scaled)
    short*    bufU    = (short*)carve((size_t)N * K * 2);    // u (bf16)
    short*    bufLast = (short*)carve((size_t)N * K * 2);    // last (bf16)
    short*    w1t     = (short*)carve((size_t)L * K * DLM * 2);
    short*    w2t     = (short*)carve((size_t)L * K * K * 2);
    short*    gw1t    = (short*)carve((size_t)L * H * K * 2);  // [L][256][128]
    short*    gw2t    = (short*)carve((size_t)L * K * H * 2);  // [L][128][256]
    (void)ws_size; (void)n_in; (void)out_size;

    // graph prep
    hipMemsetAsync(bin_cnt, 0, 4096 * 4, stream);
    hipMemsetAsync(map_idx, 0xFF, (size_t)N * 4, stream);
    hipMemsetAsync(pcnt, 0, (size_t)B * 4, stream);
    map_scatter_k<<<dim3((B + 255) / 256), 256, 0, stream>>>(mapping, map_idx, B);
    bin_count_k<<<dim3((E + 32767) / 32768), 1024, 0, stream>>>(ei + E, E, bin_cnt);
    scan_bins_k<<<dim3(1), 1024, 0, stream>>>(bin_cnt, bin_off, bin_cur);
    bin_scatter_k<<<dim3((E + 255) / 256), 256, 0, stream>>>(ei, E, map_idx, bin_cur,
                                                             pairs, pcnt, pnb);
    bin_csr_k<<<dim3(NBINS), 256, 0, stream>>>(pairs, bin_off, csr_in, in_off,
                                               dis, N);

    // weight transpose + bf16 convert (batched over layers)
    transpose_wb_k<<<dim3((L * DLM * K + 255) / 256), 256, 0, stream>>>(pW1, w1t, L, DLM, K);
    transpose_wb_k<<<dim3((L * K * K + 255) / 256), 256, 0, stream>>>(pW2, w2t, L, K, K);
    transpose_wb_k<<<dim3((L * K * H + 255) / 256), 256, 0, stream>>>(gW1, gw1t, L, K, H);
    transpose_wb_k<<<dim3((L * H * K + 255) / 256), 256, 0, stream>>>(gW2, gw2t, L, H, K);

    const int nblk64  = (N + 63) / 64;
    const int nblk128 = (N + 127) / 128;

    // layers
    for (int i = 0; i < L; ++i) {
        proj_fused_k<<<dim3(nblk128), 256, 0, stream>>>(
            hidden + (size_t)i * N * DLM,
            w1t + (size_t)i * K * DLM,
            pb1 + (size_t)i * K,
            lng + (size_t)i * K,
            lnb + (size_t)i * K,
            w2t + (size_t)i * K * K,
            pb2 + (size_t)i * K,
            alphas, i,
            (i > 0) ? (const unsigned short*)bufLast : nullptr,
            dis,
            bufA, N);

        // u = A_hat-normalized sum of pre-scaled h'   (bf16 -> bf16)
        agg_k<<<dim3((N + 3) / 4), 256, 0, stream>>>(
            (const unsigned*)bufA, (unsigned*)bufU, in_off, csr_in, dis, nullptr, N);
        // v' = dis * (relu(u @ gW1 + gb1) @ gW2)   (fused, z in LDS)
        gcn_mlp_k<<<dim3(nblk64), 256, 0, stream>>>(
            bufU, gw1t + (size_t)i * H * K, gb1 + (size_t)i * H,
            gw2t + (size_t)i * K * H, dis, bufA, N);
        // last = A_hat-normalized sum of v' + gb2   (bf16 -> bf16)
        agg_k<<<dim3((N + 3) / 4), 256, 0, stream>>>(
            (const unsigned*)bufA, (unsigned*)bufLast, in_off, csr_in, dis,
            gb2 + (size_t)i * K, N);
    }

    // pooling + classifier
    pool_clf_k<<<dim3(B), 128, 0, stream>>>((const unsigned short*)bufLast,
                                            mapping, map_idx, pcnt, pnb,
                                            clfW, clfb, (float*)d_out, C);
}